// Round 1
// baseline (730.090 us; speedup 1.0000x reference)
//
#include <hip/hip_runtime.h>

// AttentionCTS: qkv proj -> depthwise 3x3 conv -> temporal mix -> L2-norm
// q,k -> softmax(q k^T * temp) v -> out proj.   All f32 (no fp32 MFMA on CDNA4).

#define BB   4
#define DIM  64
#define HEADS 4
#define TT   10
#define HH   64
#define WW2  64
#define HW   4096          // HH*WW2
#define CPH  16            // DIM/HEADS
#define NQ   160           // CPH*TT
#define C3   192           // 3*DIM

// ---------------- Kernel 1/6: pointwise projection (templated on out-channels) ---
// out[b,o,t,hw] = sum_c in[b,c,t,hw] * w[o*CIN+c].   CIN=64 fixed.
template<int COUT>
__global__ __launch_bounds__(256) void k_proj(const float* __restrict__ x,
                                              const float* __restrict__ w,
                                              float* __restrict__ out) {
    int p   = blockIdx.x * 256 + threadIdx.x;        // position over (b,t,hw)
    int b   = p / (TT * HW);
    int rem = p - b * (TT * HW);
    int t   = rem >> 12;
    int hw  = rem & 4095;
    const float* xp = x + ((size_t)(b * DIM) * TT + t) * HW + hw;
    float xr[DIM];
#pragma unroll
    for (int c = 0; c < DIM; ++c) xr[c] = xp[(size_t)c * TT * HW];
    float* op = out + ((size_t)(b * COUT) * TT + t) * HW + hw;
    for (int o = 0; o < COUT; ++o) {
        const float* wr = w + o * DIM;               // uniform -> s_load
        float acc = 0.f;
#pragma unroll
        for (int c = 0; c < DIM; ++c) acc += xr[c] * wr[c];
        op[(size_t)o * TT * HW] = acc;
    }
}

// ---------------- Kernel 2: depthwise 3x3 conv + temporal mix + q/k sumsq -------
// block = (b, c, 4-row h-tile); 256 thr = 64w x 4h
__global__ __launch_bounds__(256) void k_conv_temporal(const float* __restrict__ A,
                                                       const float* __restrict__ wdw,
                                                       const float* __restrict__ wt,
                                                       const float* __restrict__ bt,
                                                       float* __restrict__ Bq,
                                                       float* __restrict__ nbuf) {
    __shared__ float tile[6][66];
    int blk = blockIdx.x;                 // ((b*C3)+c)*16 + ht
    int ht  = blk & 15;
    int c   = (blk >> 4) % C3;
    int b   = blk / (16 * C3);
    int h0  = ht * 4;
    int tid = threadIdx.x;
    int wq  = tid & 63;
    int hq  = tid >> 6;

    float wd9[9];
#pragma unroll
    for (int k = 0; k < 9; ++k) wd9[k] = wdw[c * 9 + k];   // uniform

    const float* Abase = A + (size_t)(b * C3 + c) * TT * HW;
    float cv[TT];
#pragma unroll
    for (int t = 0; t < TT; ++t) {
        __syncthreads();
        // stage 6x66 halo tile (zero-padded)
#pragma unroll
        for (int ii = 0; ii < 2; ++ii) {
            int idx = tid + ii * 256;
            if (idx < 396) {
                int row = idx / 66;
                int col = idx - row * 66 - 1;        // -1..64
                int gh  = h0 - 1 + row;
                float v = 0.f;
                if (gh >= 0 && gh < HH && col >= 0 && col < WW2)
                    v = Abase[(size_t)t * HW + gh * WW2 + col];
                tile[row][col + 1] = v;
            }
        }
        __syncthreads();
        float s0 = 0.f;
#pragma unroll
        for (int ky = 0; ky < 3; ++ky)
#pragma unroll
            for (int kx = 0; kx < 3; ++kx)
                s0 += tile[hq + ky][wq + kx] * wd9[ky * 3 + kx];
        cv[t] = s0;
    }

    size_t obase = (size_t)(b * C3 + c) * TT * HW + (h0 + hq) * WW2 + wq;
#pragma unroll
    for (int s = 0; s < TT; ++s) {
        float ov = bt[s];
#pragma unroll
        for (int t = 0; t < TT; ++t) ov += cv[t] * wt[s * TT + t];
        Bq[obase + (size_t)s * HW] = ov;
        if (c < 128) {                                // q or k row: accumulate sumsq
            float ss = ov * ov;
#pragma unroll
            for (int off = 32; off > 0; off >>= 1) ss += __shfl_xor(ss, off);
            if ((tid & 63) == 0)
                atomicAdd(&nbuf[(size_t)(b * 128 + c) * TT + s], ss);
        }
    }
}

// ---------------- Kernel 3: S = (q_hat k_hat^T) * temperature --------------------
// grid = 16 bh * 5 ntile * 5 mtile; 32x32 S-tile; 2x2 outputs/thread
__global__ __launch_bounds__(256) void k_scores(const float* __restrict__ Bq,
                                                const float* __restrict__ nbuf,
                                                const float* __restrict__ temp,
                                                float* __restrict__ S) {
    __shared__ float ldsQ[32 * 68];
    __shared__ float ldsK[32 * 68];
    int blk = blockIdx.x;
    int bh  = blk / 25;
    int rr  = blk - bh * 25;
    int nt  = rr / 5, mt = rr - nt * 5;
    int b   = bh >> 2, h = bh & 3;
    const float* Qb = Bq + ((size_t)(b * C3 + h * CPH) * TT) * HW + (size_t)nt * 32 * HW;
    const float* Kb = Bq + ((size_t)(b * C3 + 64 + h * CPH) * TT) * HW + (size_t)mt * 32 * HW;
    int tid = threadIdx.x;
    int r   = tid >> 3, cg = (tid & 7) * 8;
    int np  = (tid >> 4) * 2, mp = (tid & 15) * 2;
    float a00 = 0, a01 = 0, a10 = 0, a11 = 0;
    for (int d0 = 0; d0 < HW; d0 += 64) {
        __syncthreads();
        float4 q0 = *(const float4*)(Qb + (size_t)r * HW + d0 + cg);
        float4 q1 = *(const float4*)(Qb + (size_t)r * HW + d0 + cg + 4);
        float4 k0 = *(const float4*)(Kb + (size_t)r * HW + d0 + cg);
        float4 k1 = *(const float4*)(Kb + (size_t)r * HW + d0 + cg + 4);
        *(float4*)(ldsQ + r * 68 + cg)     = q0;
        *(float4*)(ldsQ + r * 68 + cg + 4) = q1;
        *(float4*)(ldsK + r * 68 + cg)     = k0;
        *(float4*)(ldsK + r * 68 + cg + 4) = k1;
        __syncthreads();
#pragma unroll
        for (int dd = 0; dd < 64; dd += 4) {
            float4 qa = *(const float4*)(ldsQ + np * 68 + dd);
            float4 qb = *(const float4*)(ldsQ + (np + 1) * 68 + dd);
            float4 ka = *(const float4*)(ldsK + mp * 68 + dd);
            float4 kb = *(const float4*)(ldsK + (mp + 1) * 68 + dd);
            a00 += qa.x * ka.x + qa.y * ka.y + qa.z * ka.z + qa.w * ka.w;
            a01 += qa.x * kb.x + qa.y * kb.y + qa.z * kb.z + qa.w * kb.w;
            a10 += qb.x * ka.x + qb.y * ka.y + qb.z * ka.z + qb.w * ka.w;
            a11 += qb.x * kb.x + qb.y * kb.y + qb.z * kb.z + qb.w * kb.w;
        }
    }
    int n = nt * 32 + np, m = mt * 32 + mp;
    float tp = temp[h];
    const float eps = 1e-12f;
    float iq0 = 1.f / fmaxf(sqrtf(nbuf[b * 1280 + h * 160 + n]),       eps);
    float iq1 = 1.f / fmaxf(sqrtf(nbuf[b * 1280 + h * 160 + n + 1]),   eps);
    float ik0 = 1.f / fmaxf(sqrtf(nbuf[b * 1280 + 640 + h * 160 + m]),     eps);
    float ik1 = 1.f / fmaxf(sqrtf(nbuf[b * 1280 + 640 + h * 160 + m + 1]), eps);
    size_t sb = ((size_t)bh * NQ + n) * NQ + m;
    S[sb]          = a00 * iq0 * ik0 * tp;
    S[sb + 1]      = a01 * iq0 * ik1 * tp;
    S[sb + NQ]     = a10 * iq1 * ik0 * tp;
    S[sb + NQ + 1] = a11 * iq1 * ik1 * tp;
}

// ---------------- Kernel 4: softmax over m, writes P^T ---------------------------
__global__ __launch_bounds__(256) void k_softmax(const float* __restrict__ S,
                                                 float* __restrict__ PT) {
    int r    = blockIdx.x * 4 + (threadIdx.x >> 6);   // row id 0..2559 (= bh*160+n)
    int lane = threadIdx.x & 63;
    const float* Srow = S + (size_t)r * NQ;
    float v0 = Srow[lane];
    float v1 = Srow[lane + 64];
    float v2 = (lane < 32) ? Srow[lane + 128] : -1e30f;
    float mx = fmaxf(fmaxf(v0, v1), v2);
#pragma unroll
    for (int off = 32; off > 0; off >>= 1) mx = fmaxf(mx, __shfl_xor(mx, off));
    float e0 = expf(v0 - mx), e1 = expf(v1 - mx);
    float e2 = (lane < 32) ? expf(v2 - mx) : 0.f;
    float sm = e0 + e1 + e2;
#pragma unroll
    for (int off = 32; off > 0; off >>= 1) sm += __shfl_xor(sm, off);
    float inv = 1.f / sm;
    int bh = r / NQ, n = r - bh * NQ;
    float* Pb = PT + (size_t)bh * NQ * NQ + n;
    Pb[(size_t)lane * NQ]        = e0 * inv;
    Pb[(size_t)(lane + 64) * NQ] = e1 * inv;
    if (lane < 32) Pb[(size_t)(lane + 128) * NQ] = e2 * inv;
}

// ---------------- Kernel 5: O = P V ----------------------------------------------
// grid = bh(16) * dtile(16 x 256 cols) * nhalf(2); P^T rows via scalar loads
__global__ __launch_bounds__(256) void k_pv(const float* __restrict__ Bq,
                                            const float* __restrict__ PT,
                                            float* __restrict__ O) {
    int blk  = blockIdx.x;
    int half = blk & 1;
    int dt   = (blk >> 1) & 15;
    int bh   = blk >> 5;
    int b    = bh >> 2, h = bh & 3;
    int d    = dt * 256 + threadIdx.x;
    const float* Vb  = Bq + ((size_t)(b * C3 + 128 + h * CPH) * TT) * HW;
    const float* PTb = PT + (size_t)bh * NQ * NQ;
    float* Ob = O + ((size_t)(b * DIM + h * CPH) * TT) * HW;
#pragma unroll
    for (int pass = 0; pass < 2; ++pass) {
        int n0 = half * 80 + pass * 40;
        float acc[40];
#pragma unroll
        for (int j = 0; j < 40; ++j) acc[j] = 0.f;
        for (int m = 0; m < NQ; ++m) {
            float vv = Vb[(size_t)m * HW + d];
            const float* pr = PTb + m * NQ + n0;      // uniform -> s_load
#pragma unroll
            for (int j = 0; j < 40; ++j) acc[j] += pr[j] * vv;
        }
#pragma unroll
        for (int j = 0; j < 40; ++j) Ob[(size_t)(n0 + j) * HW + d] = acc[j];
    }
}

extern "C" void kernel_launch(void* const* d_in, const int* in_sizes, int n_in,
                              void* d_out, int out_size, void* d_ws, size_t ws_size,
                              hipStream_t stream) {
    const float* x    = (const float*)d_in[0];
    const float* wqkv = (const float*)d_in[1];
    const float* wdw  = (const float*)d_in[2];
    const float* wt   = (const float*)d_in[3];
    const float* bt   = (const float*)d_in[4];
    const float* temp = (const float*)d_in[5];
    const float* wout = (const float*)d_in[6];
    float* out = (float*)d_out;

    const size_t SA = (size_t)BB * C3 * TT * HW;       // 31,457,280 floats
    const size_t SN = (size_t)BB * 128 * TT;           // 5,120
    const size_t SS = (size_t)16 * NQ * NQ;            // 409,600
    const size_t SO = (size_t)BB * DIM * TT * HW;      // 10,485,760

    float* bufA = (float*)d_ws;          // region0: qkv-proj out; later reused
    float* bufB = bufA + SA;             // conv+temporal out (q|k|v)
    float* nbuf = bufB + SA;             // q/k row sumsq
    // reuse region0 after k_conv_temporal consumed bufA:
    float* Obuf = bufA;                  // attn output (SO floats)
    float* Sbuf = bufA + SO;             // scores     (SS floats)
    float* PTbf = Sbuf + SS;             // P^T        (SS floats)

    if (ws_size < (2 * SA + SN) * sizeof(float)) return;  // scratch too small

    hipMemsetAsync(nbuf, 0, SN * sizeof(float), stream);

    k_proj<C3><<<dim3(640), dim3(256), 0, stream>>>(x, wqkv, bufA);
    k_conv_temporal<<<dim3(12288), dim3(256), 0, stream>>>(bufA, wdw, wt, bt, bufB, nbuf);
    k_scores<<<dim3(400), dim3(256), 0, stream>>>(bufB, nbuf, temp, Sbuf);
    k_softmax<<<dim3(640), dim3(256), 0, stream>>>(Sbuf, PTbf);
    k_pv<<<dim3(512), dim3(256), 0, stream>>>(bufB, PTbf, Obuf);
    k_proj<DIM><<<dim3(640), dim3(256), 0, stream>>>(Obuf, wout, out);
}

// Round 2
// 698.319 us; speedup vs baseline: 1.0455x; 1.0455x over previous
//
#include <hip/hip_runtime.h>

// AttentionCTS: qkv proj -> depthwise 3x3 conv -> temporal mix -> L2-norm
// q,k -> softmax(q k^T * temp) v -> out proj.   All f32 (no fp32 MFMA on CDNA4).

#define BB   4
#define DIM  64
#define HEADS 4
#define TT   10
#define HH   64
#define WW2  64
#define HW   4096          // HH*WW2
#define CPH  16            // DIM/HEADS
#define NQ   160           // CPH*TT
#define C3   192           // 3*DIM

// ---------------- Kernel 1/6: pointwise projection (templated on out-channels) ---
// out[b,o,t,hw] = sum_c in[b,c,t,hw] * w[o*CIN+c].   CIN=64 fixed.
template<int COUT>
__global__ __launch_bounds__(256) void k_proj(const float* __restrict__ x,
                                              const float* __restrict__ w,
                                              float* __restrict__ out) {
    int p   = blockIdx.x * 256 + threadIdx.x;        // position over (b,t,hw)
    int b   = p / (TT * HW);
    int rem = p - b * (TT * HW);
    int t   = rem >> 12;
    int hw  = rem & 4095;
    const float* xp = x + ((size_t)(b * DIM) * TT + t) * HW + hw;
    float xr[DIM];
#pragma unroll
    for (int c = 0; c < DIM; ++c) xr[c] = xp[(size_t)c * TT * HW];
    float* op = out + ((size_t)(b * COUT) * TT + t) * HW + hw;
    for (int o = 0; o < COUT; ++o) {
        const float* wr = w + o * DIM;               // uniform -> s_load
        float acc = 0.f;
#pragma unroll
        for (int c = 0; c < DIM; ++c) acc += xr[c] * wr[c];
        op[(size_t)o * TT * HW] = acc;
    }
}

// ---------------- Kernel 2: depthwise 3x3 conv + temporal mix + q/k sumsq -------
// One wave per (b,c,h) row; lane = w. No LDS, no barriers.
// Halo via 3 coalesced row loads + shfl_up/shfl_down for w+-1.
__global__ __launch_bounds__(256) void k_conv_temporal(const float* __restrict__ A,
                                                       const float* __restrict__ wdw,
                                                       const float* __restrict__ wt,
                                                       const float* __restrict__ bt,
                                                       float* __restrict__ Bq,
                                                       float* __restrict__ nbuf) {
    int tid  = threadIdx.x;
    int lane = tid & 63;
    int wv   = tid >> 6;
    int blk  = blockIdx.x;                 // ((b*C3)+c)*16 + ht
    int ht   = blk & 15;
    int c    = (blk >> 4) % C3;
    int b    = blk / (16 * C3);
    int h    = ht * 4 + wv;

    float wd[9];
#pragma unroll
    for (int k = 0; k < 9; ++k) wd[k] = wdw[c * 9 + k];    // uniform -> sgpr

    const float* Ab = A + (size_t)(b * C3 + c) * TT * HW + h * WW2;
    bool hasU = (h > 0), hasD = (h < HH - 1);

    float cv[TT];
#pragma unroll
    for (int t = 0; t < TT; ++t) {
        const float* row = Ab + (size_t)t * HW;
        float cu = hasU ? row[lane - WW2] : 0.f;
        float cc = row[lane];
        float cd = hasD ? row[lane + WW2] : 0.f;
        float lu = __shfl_up(cu, 1);  if (lane == 0)  lu = 0.f;
        float ru = __shfl_down(cu, 1); if (lane == 63) ru = 0.f;
        float lc = __shfl_up(cc, 1);  if (lane == 0)  lc = 0.f;
        float rc = __shfl_down(cc, 1); if (lane == 63) rc = 0.f;
        float ld = __shfl_up(cd, 1);  if (lane == 0)  ld = 0.f;
        float rd = __shfl_down(cd, 1); if (lane == 63) rd = 0.f;
        cv[t] = lu * wd[0] + cu * wd[1] + ru * wd[2]
              + lc * wd[3] + cc * wd[4] + rc * wd[5]
              + ld * wd[6] + cd * wd[7] + rd * wd[8];
    }

    size_t obase = (size_t)(b * C3 + c) * TT * HW + h * WW2 + lane;
#pragma unroll
    for (int s = 0; s < TT; ++s) {
        float ov = bt[s];
#pragma unroll
        for (int t = 0; t < TT; ++t) ov += cv[t] * wt[s * TT + t];
        Bq[obase + (size_t)s * HW] = ov;
        if (c < 128) {                                // q or k row: accumulate sumsq
            float ss = ov * ov;
#pragma unroll
            for (int off = 32; off > 0; off >>= 1) ss += __shfl_xor(ss, off);
            if (lane == 0)
                atomicAdd(&nbuf[(size_t)(b * 128 + c) * TT + s], ss);
        }
    }
}

// ---------------- Kernel 3: S = (q_hat k_hat^T) * temperature --------------------
// grid = 16 bh * 5 ntile * 5 mtile; 32x32 S-tile; 2x2 outputs/thread
__global__ __launch_bounds__(256) void k_scores(const float* __restrict__ Bq,
                                                const float* __restrict__ nbuf,
                                                const float* __restrict__ temp,
                                                float* __restrict__ S) {
    __shared__ float ldsQ[32 * 68];
    __shared__ float ldsK[32 * 68];
    int blk = blockIdx.x;
    int bh  = blk / 25;
    int rr  = blk - bh * 25;
    int nt  = rr / 5, mt = rr - nt * 5;
    int b   = bh >> 2, h = bh & 3;
    const float* Qb = Bq + ((size_t)(b * C3 + h * CPH) * TT) * HW + (size_t)nt * 32 * HW;
    const float* Kb = Bq + ((size_t)(b * C3 + 64 + h * CPH) * TT) * HW + (size_t)mt * 32 * HW;
    int tid = threadIdx.x;
    int r   = tid >> 3, cg = (tid & 7) * 8;
    int np  = (tid >> 4) * 2, mp = (tid & 15) * 2;
    float a00 = 0, a01 = 0, a10 = 0, a11 = 0;
    for (int d0 = 0; d0 < HW; d0 += 64) {
        __syncthreads();
        float4 q0 = *(const float4*)(Qb + (size_t)r * HW + d0 + cg);
        float4 q1 = *(const float4*)(Qb + (size_t)r * HW + d0 + cg + 4);
        float4 k0 = *(const float4*)(Kb + (size_t)r * HW + d0 + cg);
        float4 k1 = *(const float4*)(Kb + (size_t)r * HW + d0 + cg + 4);
        *(float4*)(ldsQ + r * 68 + cg)     = q0;
        *(float4*)(ldsQ + r * 68 + cg + 4) = q1;
        *(float4*)(ldsK + r * 68 + cg)     = k0;
        *(float4*)(ldsK + r * 68 + cg + 4) = k1;
        __syncthreads();
#pragma unroll
        for (int dd = 0; dd < 64; dd += 4) {
            float4 qa = *(const float4*)(ldsQ + np * 68 + dd);
            float4 qb = *(const float4*)(ldsQ + (np + 1) * 68 + dd);
            float4 ka = *(const float4*)(ldsK + mp * 68 + dd);
            float4 kb = *(const float4*)(ldsK + (mp + 1) * 68 + dd);
            a00 += qa.x * ka.x + qa.y * ka.y + qa.z * ka.z + qa.w * ka.w;
            a01 += qa.x * kb.x + qa.y * kb.y + qa.z * kb.z + qa.w * kb.w;
            a10 += qb.x * ka.x + qb.y * ka.y + qb.z * ka.z + qb.w * ka.w;
            a11 += qb.x * kb.x + qb.y * kb.y + qb.z * kb.z + qb.w * kb.w;
        }
    }
    int n = nt * 32 + np, m = mt * 32 + mp;
    float tp = temp[h];
    const float eps = 1e-12f;
    float iq0 = 1.f / fmaxf(sqrtf(nbuf[b * 1280 + h * 160 + n]),       eps);
    float iq1 = 1.f / fmaxf(sqrtf(nbuf[b * 1280 + h * 160 + n + 1]),   eps);
    float ik0 = 1.f / fmaxf(sqrtf(nbuf[b * 1280 + 640 + h * 160 + m]),     eps);
    float ik1 = 1.f / fmaxf(sqrtf(nbuf[b * 1280 + 640 + h * 160 + m + 1]), eps);
    size_t sb = ((size_t)bh * NQ + n) * NQ + m;
    S[sb]          = a00 * iq0 * ik0 * tp;
    S[sb + 1]      = a01 * iq0 * ik1 * tp;
    S[sb + NQ]     = a10 * iq1 * ik0 * tp;
    S[sb + NQ + 1] = a11 * iq1 * ik1 * tp;
}

// ---------------- Kernel 4: softmax over m, writes P^T ---------------------------
__global__ __launch_bounds__(256) void k_softmax(const float* __restrict__ S,
                                                 float* __restrict__ PT) {
    int r    = blockIdx.x * 4 + (threadIdx.x >> 6);   // row id 0..2559 (= bh*160+n)
    int lane = threadIdx.x & 63;
    const float* Srow = S + (size_t)r * NQ;
    float v0 = Srow[lane];
    float v1 = Srow[lane + 64];
    float v2 = (lane < 32) ? Srow[lane + 128] : -1e30f;
    float mx = fmaxf(fmaxf(v0, v1), v2);
#pragma unroll
    for (int off = 32; off > 0; off >>= 1) mx = fmaxf(mx, __shfl_xor(mx, off));
    float e0 = expf(v0 - mx), e1 = expf(v1 - mx);
    float e2 = (lane < 32) ? expf(v2 - mx) : 0.f;
    float sm = e0 + e1 + e2;
#pragma unroll
    for (int off = 32; off > 0; off >>= 1) sm += __shfl_xor(sm, off);
    float inv = 1.f / sm;
    int bh = r / NQ, n = r - bh * NQ;
    float* Pb = PT + (size_t)bh * NQ * NQ + n;
    Pb[(size_t)lane * NQ]        = e0 * inv;
    Pb[(size_t)(lane + 64) * NQ] = e1 * inv;
    if (lane < 32) Pb[(size_t)(lane + 128) * NQ] = e2 * inv;
}

// ---------------- Kernel 5: O = P V ----------------------------------------------
// grid = bh(16) * dtile(16 x 256 cols) * nhalf(2); P^T rows via scalar loads
__global__ __launch_bounds__(256) void k_pv(const float* __restrict__ Bq,
                                            const float* __restrict__ PT,
                                            float* __restrict__ O) {
    int blk  = blockIdx.x;
    int half = blk & 1;
    int dt   = (blk >> 1) & 15;
    int bh   = blk >> 5;
    int b    = bh >> 2, h = bh & 3;
    int d    = dt * 256 + threadIdx.x;
    const float* Vb  = Bq + ((size_t)(b * C3 + 128 + h * CPH) * TT) * HW;
    const float* PTb = PT + (size_t)bh * NQ * NQ;
    float* Ob = O + ((size_t)(b * DIM + h * CPH) * TT) * HW;
#pragma unroll
    for (int pass = 0; pass < 2; ++pass) {
        int n0 = half * 80 + pass * 40;
        float acc[40];
#pragma unroll
        for (int j = 0; j < 40; ++j) acc[j] = 0.f;
        for (int m = 0; m < NQ; ++m) {
            float vv = Vb[(size_t)m * HW + d];
            const float* pr = PTb + m * NQ + n0;      // uniform -> s_load
#pragma unroll
            for (int j = 0; j < 40; ++j) acc[j] += pr[j] * vv;
        }
#pragma unroll
        for (int j = 0; j < 40; ++j) Ob[(size_t)(n0 + j) * HW + d] = acc[j];
    }
}

extern "C" void kernel_launch(void* const* d_in, const int* in_sizes, int n_in,
                              void* d_out, int out_size, void* d_ws, size_t ws_size,
                              hipStream_t stream) {
    const float* x    = (const float*)d_in[0];
    const float* wqkv = (const float*)d_in[1];
    const float* wdw  = (const float*)d_in[2];
    const float* wt   = (const float*)d_in[3];
    const float* bt   = (const float*)d_in[4];
    const float* temp = (const float*)d_in[5];
    const float* wout = (const float*)d_in[6];
    float* out = (float*)d_out;

    const size_t SA = (size_t)BB * C3 * TT * HW;       // 31,457,280 floats
    const size_t SN = (size_t)BB * 128 * TT;           // 5,120
    const size_t SS = (size_t)16 * NQ * NQ;            // 409,600
    const size_t SO = (size_t)BB * DIM * TT * HW;      // 10,485,760

    float* bufA = (float*)d_ws;          // region0: qkv-proj out; later reused
    float* bufB = bufA + SA;             // conv+temporal out (q|k|v)
    float* nbuf = bufB + SA;             // q/k row sumsq
    // reuse region0 after k_conv_temporal consumed bufA:
    float* Obuf = bufA;                  // attn output (SO floats)
    float* Sbuf = bufA + SO;             // scores     (SS floats)
    float* PTbf = Sbuf + SS;             // P^T        (SS floats)

    if (ws_size < (2 * SA + SN) * sizeof(float)) return;  // scratch too small

    hipMemsetAsync(nbuf, 0, SN * sizeof(float), stream);

    k_proj<C3><<<dim3(640), dim3(256), 0, stream>>>(x, wqkv, bufA);
    k_conv_temporal<<<dim3(12288), dim3(256), 0, stream>>>(bufA, wdw, wt, bt, bufB, nbuf);
    k_scores<<<dim3(400), dim3(256), 0, stream>>>(bufB, nbuf, temp, Sbuf);
    k_softmax<<<dim3(640), dim3(256), 0, stream>>>(Sbuf, PTbf);
    k_pv<<<dim3(512), dim3(256), 0, stream>>>(bufB, PTbf, Obuf);
    k_proj<DIM><<<dim3(640), dim3(256), 0, stream>>>(Obuf, wout, out);
}

// Round 4
// 619.997 us; speedup vs baseline: 1.1776x; 1.1263x over previous
//
#include <hip/hip_runtime.h>

// AttentionCTS: qkv proj -> depthwise 3x3 conv -> temporal mix -> L2-norm
// q,k -> softmax(q k^T * temp) v -> out proj.   All f32 (no fp32 MFMA on CDNA4).

#define BB   4
#define DIM  64
#define HEADS 4
#define TT   10
#define HH   64
#define WW2  64
#define HW   4096          // HH*WW2
#define CPH  16            // DIM/HEADS
#define NQ   160           // CPH*TT
#define C3   192           // 3*DIM

// ---------------- Kernel 1/6: pointwise projection -------------------------------
// out[b,o,t,hw] = sum_c in[b,c,t,hw] * w[o*DIM+c].  COUT split over blockIdx.y
// in CHUNK-sized pieces (grid-level parallelism); 4-way partial sums (ILP).
template<int CHUNK>
__global__ __launch_bounds__(256) void k_proj(const float* __restrict__ x,
                                              const float* __restrict__ w,
                                              float* __restrict__ out,
                                              int cout_total) {
    int p   = blockIdx.x * 256 + threadIdx.x;        // position over (b,t,hw)
    int b   = p / (TT * HW);
    int rem = p - b * (TT * HW);
    int t   = rem >> 12;
    int hw  = rem & 4095;
    int o0  = blockIdx.y * CHUNK;
    const float* xp = x + ((size_t)(b * DIM) * TT + t) * HW + hw;
    float xr[DIM];
#pragma unroll
    for (int c = 0; c < DIM; ++c) xr[c] = xp[(size_t)c * TT * HW];
    float* op = out + ((size_t)b * cout_total * TT + t) * HW + hw;
    for (int oo = 0; oo < CHUNK; ++oo) {
        int o = o0 + oo;
        const float* wr = w + o * DIM;               // uniform -> s_load
        float a0 = 0.f, a1 = 0.f, a2 = 0.f, a3 = 0.f;
#pragma unroll
        for (int c = 0; c < DIM; c += 4) {
            a0 += xr[c]     * wr[c];
            a1 += xr[c + 1] * wr[c + 1];
            a2 += xr[c + 2] * wr[c + 2];
            a3 += xr[c + 3] * wr[c + 3];
        }
        op[(size_t)o * TT * HW] = (a0 + a1) + (a2 + a3);
    }
}

// ---------------- Kernel 2: depthwise 3x3 conv + temporal mix + q/k sumsq -------
// One wave per (b,c,h) row; lane = w. No LDS, no barriers.
// Reduce restructured: all 10 ov first, then 6 butterfly levels x 10 values (ILP).
__global__ __launch_bounds__(256) void k_conv_temporal(const float* __restrict__ A,
                                                       const float* __restrict__ wdw,
                                                       const float* __restrict__ wt,
                                                       const float* __restrict__ bt,
                                                       float* __restrict__ Bq,
                                                       float* __restrict__ nbuf) {
    int tid  = threadIdx.x;
    int lane = tid & 63;
    int wv   = tid >> 6;
    int blk  = blockIdx.x;                 // ((b*C3)+c)*16 + ht
    int ht   = blk & 15;
    int c    = (blk >> 4) % C3;
    int b    = blk / (16 * C3);
    int h    = ht * 4 + wv;

    float wd[9];
#pragma unroll
    for (int k = 0; k < 9; ++k) wd[k] = wdw[c * 9 + k];    // uniform -> sgpr

    const float* Ab = A + (size_t)(b * C3 + c) * TT * HW + h * WW2;
    bool hasU = (h > 0), hasD = (h < HH - 1);

    float cv[TT];
#pragma unroll
    for (int t = 0; t < TT; ++t) {
        const float* row = Ab + (size_t)t * HW;
        float cu = hasU ? row[lane - WW2] : 0.f;
        float cc = row[lane];
        float cd = hasD ? row[lane + WW2] : 0.f;
        float lu = __shfl_up(cu, 1);  if (lane == 0)  lu = 0.f;
        float ru = __shfl_down(cu, 1); if (lane == 63) ru = 0.f;
        float lc = __shfl_up(cc, 1);  if (lane == 0)  lc = 0.f;
        float rc = __shfl_down(cc, 1); if (lane == 63) rc = 0.f;
        float ld = __shfl_up(cd, 1);  if (lane == 0)  ld = 0.f;
        float rd = __shfl_down(cd, 1); if (lane == 63) rd = 0.f;
        cv[t] = lu * wd[0] + cu * wd[1] + ru * wd[2]
              + lc * wd[3] + cc * wd[4] + rc * wd[5]
              + ld * wd[6] + cd * wd[7] + rd * wd[8];
    }

    // temporal mix: 10-way independent accumulators
    float ov[TT];
#pragma unroll
    for (int s = 0; s < TT; ++s) {
        float v = bt[s];
#pragma unroll
        for (int t = 0; t < TT; ++t) v += cv[t] * wt[s * TT + t];
        ov[s] = v;
    }

    size_t obase = (size_t)(b * C3 + c) * TT * HW + h * WW2 + lane;
#pragma unroll
    for (int s = 0; s < TT; ++s) Bq[obase + (size_t)s * HW] = ov[s];

    if (c < 128) {                          // q or k row: accumulate sumsq
        float ss[TT];
#pragma unroll
        for (int s = 0; s < TT; ++s) ss[s] = ov[s] * ov[s];
#pragma unroll
        for (int off = 32; off > 0; off >>= 1) {
#pragma unroll
            for (int s = 0; s < TT; ++s) ss[s] += __shfl_xor(ss[s], off);
        }
        if (lane == 0) {
#pragma unroll
            for (int s = 0; s < TT; ++s)
                atomicAdd(&nbuf[(size_t)(b * 128 + c) * TT + s], ss[s]);
        }
    }
}

// ---------------- Kernel 3: partial scores S_part[split] = q k^T over d-chunk ----
// grid = (16 bh * 25 tiles, 4 splits); 32x32 S-tile; 2x2 outputs/thread.
// Normalization/temperature applied later in k_softmax.
__global__ __launch_bounds__(256) void k_scores(const float* __restrict__ Bq,
                                                float* __restrict__ Spart) {
    __shared__ float ldsQ[32 * 68];
    __shared__ float ldsK[32 * 68];
    int blk = blockIdx.x;
    int bh  = blk / 25;
    int rr  = blk - bh * 25;
    int nt  = rr / 5, mt = rr - nt * 5;
    int b   = bh >> 2, h = bh & 3;
    int split = blockIdx.y;
    const float* Qb = Bq + ((size_t)(b * C3 + h * CPH) * TT) * HW + (size_t)nt * 32 * HW;
    const float* Kb = Bq + ((size_t)(b * C3 + 64 + h * CPH) * TT) * HW + (size_t)mt * 32 * HW;
    int tid = threadIdx.x;
    int r   = tid >> 3, cg = (tid & 7) * 8;
    int np  = (tid >> 4) * 2, mp = (tid & 15) * 2;
    float a00 = 0, a01 = 0, a10 = 0, a11 = 0;
    int dlo = split * (HW / 4), dhi = dlo + (HW / 4);
    for (int d0 = dlo; d0 < dhi; d0 += 64) {
        __syncthreads();
        float4 q0 = *(const float4*)(Qb + (size_t)r * HW + d0 + cg);
        float4 q1 = *(const float4*)(Qb + (size_t)r * HW + d0 + cg + 4);
        float4 k0 = *(const float4*)(Kb + (size_t)r * HW + d0 + cg);
        float4 k1 = *(const float4*)(Kb + (size_t)r * HW + d0 + cg + 4);
        *(float4*)(ldsQ + r * 68 + cg)     = q0;
        *(float4*)(ldsQ + r * 68 + cg + 4) = q1;
        *(float4*)(ldsK + r * 68 + cg)     = k0;
        *(float4*)(ldsK + r * 68 + cg + 4) = k1;
        __syncthreads();
#pragma unroll
        for (int dd = 0; dd < 64; dd += 4) {
            float4 qa = *(const float4*)(ldsQ + np * 68 + dd);
            float4 qb = *(const float4*)(ldsQ + (np + 1) * 68 + dd);
            float4 ka = *(const float4*)(ldsK + mp * 68 + dd);
            float4 kb = *(const float4*)(ldsK + (mp + 1) * 68 + dd);
            a00 += qa.x * ka.x + qa.y * ka.y + qa.z * ka.z + qa.w * ka.w;
            a01 += qa.x * kb.x + qa.y * kb.y + qa.z * kb.z + qa.w * kb.w;
            a10 += qb.x * ka.x + qb.y * ka.y + qb.z * ka.z + qb.w * ka.w;
            a11 += qb.x * kb.x + qb.y * kb.y + qb.z * kb.z + qb.w * kb.w;
        }
    }
    int n = nt * 32 + np, m = mt * 32 + mp;
    size_t sb = (size_t)split * (16 * NQ * NQ) + ((size_t)bh * NQ + n) * NQ + m;
    Spart[sb]          = a00;
    Spart[sb + 1]      = a01;
    Spart[sb + NQ]     = a10;
    Spart[sb + NQ + 1] = a11;
}

// ---------------- Kernel 4: sum partials, scale, softmax over m, write P^T -------
__global__ __launch_bounds__(256) void k_softmax(const float* __restrict__ Spart,
                                                 const float* __restrict__ nbuf,
                                                 const float* __restrict__ temp,
                                                 float* __restrict__ PT) {
    const int SS = 16 * NQ * NQ;
    int r    = blockIdx.x * 4 + (threadIdx.x >> 6);   // row id 0..2559 (= bh*160+n)
    int lane = threadIdx.x & 63;
    const float* Sr = Spart + (size_t)r * NQ;
    float v0 = 0.f, v1 = 0.f, v2 = 0.f;
#pragma unroll
    for (int sp = 0; sp < 4; ++sp) {
        v0 += Sr[sp * SS + lane];
        v1 += Sr[sp * SS + lane + 64];
        if (lane < 32) v2 += Sr[sp * SS + lane + 128];
    }
    int bh = r / NQ, n = r - bh * NQ;
    int b  = bh >> 2, h = bh & 3;
    const float eps = 1e-12f;
    float tp  = temp[h];
    float iqn = tp / fmaxf(sqrtf(nbuf[b * 1280 + h * 160 + n]), eps);       // uniform
    float ik0 = 1.f / fmaxf(sqrtf(nbuf[b * 1280 + 640 + h * 160 + lane]), eps);
    float ik1 = 1.f / fmaxf(sqrtf(nbuf[b * 1280 + 640 + h * 160 + lane + 64]), eps);
    float ik2 = (lane < 32) ? 1.f / fmaxf(sqrtf(nbuf[b * 1280 + 640 + h * 160 + lane + 128]), eps) : 1.f;
    v0 *= iqn * ik0;
    v1 *= iqn * ik1;
    v2 = (lane < 32) ? v2 * iqn * ik2 : -1e30f;
    float mx = fmaxf(fmaxf(v0, v1), v2);
#pragma unroll
    for (int off = 32; off > 0; off >>= 1) mx = fmaxf(mx, __shfl_xor(mx, off));
    float e0 = expf(v0 - mx), e1 = expf(v1 - mx);
    float e2 = (lane < 32) ? expf(v2 - mx) : 0.f;
    float sm = e0 + e1 + e2;
#pragma unroll
    for (int off = 32; off > 0; off >>= 1) sm += __shfl_xor(sm, off);
    float inv = 1.f / sm;
    float* Pb = PT + (size_t)bh * NQ * NQ + n;
    Pb[(size_t)lane * NQ]        = e0 * inv;
    Pb[(size_t)(lane + 64) * NQ] = e1 * inv;
    if (lane < 32) Pb[(size_t)(lane + 128) * NQ] = e2 * inv;
}

// ---------------- Kernel 5: O = P V ----------------------------------------------
// grid = bh(16) * dtile(16 x 256 cols) * nq(4 x 40 rows); P^T rows via scalar loads
__global__ __launch_bounds__(256) void k_pv(const float* __restrict__ Bq,
                                            const float* __restrict__ PT,
                                            float* __restrict__ O) {
    int blk  = blockIdx.x;
    int nq   = blk & 3;
    int dt   = (blk >> 2) & 15;
    int bh   = blk >> 6;
    int b    = bh >> 2, h = bh & 3;
    int d    = dt * 256 + threadIdx.x;
    int n0   = nq * 40;
    const float* Vb  = Bq + ((size_t)(b * C3 + 128 + h * CPH) * TT) * HW;
    const float* PTb = PT + (size_t)bh * NQ * NQ;
    float* Ob = O + ((size_t)(b * DIM + h * CPH) * TT) * HW;
    float acc[40];
#pragma unroll
    for (int j = 0; j < 40; ++j) acc[j] = 0.f;
    for (int m = 0; m < NQ; ++m) {
        float vv = Vb[(size_t)m * HW + d];
        const float* pr = PTb + m * NQ + n0;      // uniform -> s_load
#pragma unroll
        for (int j = 0; j < 40; ++j) acc[j] += pr[j] * vv;
    }
#pragma unroll
    for (int j = 0; j < 40; ++j) Ob[(size_t)(n0 + j) * HW + d] = acc[j];
}

extern "C" void kernel_launch(void* const* d_in, const int* in_sizes, int n_in,
                              void* d_out, int out_size, void* d_ws, size_t ws_size,
                              hipStream_t stream) {
    const float* x    = (const float*)d_in[0];
    const float* wqkv = (const float*)d_in[1];
    const float* wdw  = (const float*)d_in[2];
    const float* wt   = (const float*)d_in[3];
    const float* bt   = (const float*)d_in[4];
    const float* temp = (const float*)d_in[5];
    const float* wout = (const float*)d_in[6];
    float* out = (float*)d_out;

    const size_t SA = (size_t)BB * C3 * TT * HW;       // 31,457,280 floats
    const size_t SN = (size_t)BB * 128 * TT;           // 5,120
    const size_t SS = (size_t)16 * NQ * NQ;            // 409,600
    const size_t SO = (size_t)BB * DIM * TT * HW;      // 10,485,760

    float* bufA = (float*)d_ws;          // region0: qkv-proj out; later reused
    float* bufB = bufA + SA;             // conv+temporal out (q|k|v)
    float* nbuf = bufB + SA;             // q/k row sumsq
    // reuse region0 after k_conv_temporal consumed bufA:
    float* Obuf  = bufA;                 // attn output (SO floats)
    float* Spart = bufA + SO;            // partial scores (4*SS floats)
    float* PTbf  = Spart + 4 * SS;       // P^T (SS floats)

    if (ws_size < (2 * SA + SN) * sizeof(float)) return;  // scratch too small

    (void)hipMemsetAsync(nbuf, 0, SN * sizeof(float), stream);

    k_proj<64><<<dim3(640, 3), dim3(256), 0, stream>>>(x, wqkv, bufA, C3);
    k_conv_temporal<<<dim3(12288), dim3(256), 0, stream>>>(bufA, wdw, wt, bt, bufB, nbuf);
    k_scores<<<dim3(400, 4), dim3(256), 0, stream>>>(bufB, Spart);
    k_softmax<<<dim3(640), dim3(256), 0, stream>>>(Spart, nbuf, temp, PTbf);
    k_pv<<<dim3(1024), dim3(256), 0, stream>>>(bufB, PTbf, Obuf);
    k_proj<32><<<dim3(640, 2), dim3(256), 0, stream>>>(Obuf, wout, out, DIM);
}